// Round 1
// baseline (433.337 us; speedup 1.0000x reference)
//
#include <hip/hip_runtime.h>

#define NN 8192
#define EE 262144
#define IN_DIM 512
#define HD1 256
#define HD2 128

typedef __attribute__((ext_vector_type(8))) short bf16x8;
typedef __attribute__((ext_vector_type(4))) float f32x4;

__device__ inline unsigned short f2bf(float f) {
    unsigned int u = __builtin_bit_cast(unsigned int, f);
    u += 0x7fffu + ((u >> 16) & 1u);
    return (unsigned short)(u >> 16);
}

// ---------------- graph preprocessing ----------------

__global__ void deg_kernel(const int* __restrict__ src, const int* __restrict__ dst,
                           int* __restrict__ deg_out, int* __restrict__ deg_in) {
    int e = blockIdx.x * blockDim.x + threadIdx.x;
    if (e < EE) {
        atomicAdd(&deg_out[src[e]], 1);
        atomicAdd(&deg_in[dst[e]], 1);
    }
}

__global__ void norm_kernel(const int* __restrict__ deg_out, const int* __restrict__ deg_in,
                            float* __restrict__ norm_src, float* __restrict__ norm_dst) {
    int i = blockIdx.x * blockDim.x + threadIdx.x;
    if (i < NN) {
        int dout = deg_out[i]; if (dout < 1) dout = 1;
        int din  = deg_in[i];  if (din  < 1) din  = 1;
        norm_src[i] = rsqrtf((float)dout);
        norm_dst[i] = rsqrtf((float)din);
    }
}

// exclusive prefix sum of 8192 counts -> row_start[8193]; single block, 256 threads
__global__ void scan_kernel(const int* __restrict__ counts, int* __restrict__ row_start) {
    __shared__ int sums[256];
    int t = threadIdx.x;
    int base = t * 32;
    int local[32];
    int s = 0;
    for (int i = 0; i < 32; i++) { local[i] = s; s += counts[base + i]; }
    sums[t] = s;
    __syncthreads();
    for (int off = 1; off < 256; off <<= 1) {
        int v = (t >= off) ? sums[t - off] : 0;
        __syncthreads();
        sums[t] += v;
        __syncthreads();
    }
    int coff = (t == 0) ? 0 : sums[t - 1];
    for (int i = 0; i < 32; i++) row_start[base + i] = coff + local[i];
    if (t == 255) row_start[NN] = sums[255];
}

__global__ void fill_kernel(const int* __restrict__ src, const int* __restrict__ dst,
                            const int* __restrict__ row_start, int* __restrict__ cursor,
                            int* __restrict__ eidx) {
    int e = blockIdx.x * blockDim.x + threadIdx.x;
    if (e < EE) {
        int d = dst[e];
        int pos = atomicAdd(&cursor[d], 1);
        eidx[row_start[d] + pos] = src[e];
    }
}

// ---------------- casts ----------------

// xn_bf16[i][k] = bf16(features[i][k] * norm_src[i]);  float4 in, 4x bf16 out
__global__ void scale_cast_kernel(const float4* __restrict__ x, const float* __restrict__ norm_src,
                                  ushort4* __restrict__ out) {
    int idx = blockIdx.x * blockDim.x + threadIdx.x;  // over NN*IN_DIM/4
    if (idx < NN * IN_DIM / 4) {
        float ns = norm_src[idx >> 7];  // IN_DIM/4 = 128 float4 per row
        float4 v = x[idx];
        ushort4 o;
        o.x = f2bf(v.x * ns); o.y = f2bf(v.y * ns);
        o.z = f2bf(v.z * ns); o.w = f2bf(v.w * ns);
        out[idx] = o;
    }
}

// Wt[n][k] = bf16(W[k][n]);  W is [K][Nc]
__global__ void transpose_cast_kernel(const float* __restrict__ W, unsigned short* __restrict__ Wt,
                                      int K, int Nc) {
    int idx = blockIdx.x * blockDim.x + threadIdx.x;
    if (idx < K * Nc) {
        int n = idx / K;
        int k = idx - n * K;
        Wt[idx] = f2bf(W[k * Nc + n]);
    }
}

// ---------------- bf16 MFMA GEMM:  C[M][N] = A[M][K] * B[N][K]^T ----------------
// 128x128 tile per block, 4 waves (2x2) of 64x64, direct global fragment loads.
// EPI=0: store fp32.  EPI=1: store sigmoid(x).
template <int EPI>
__global__ __launch_bounds__(256) void gemm_tn(const short* __restrict__ A,
                                               const short* __restrict__ B,
                                               float* __restrict__ C, int N, int K) {
    int wave = threadIdx.x >> 6;
    int lane = threadIdx.x & 63;
    int wr = wave >> 1, wc = wave & 1;
    int row0 = blockIdx.y * 128 + wr * 64;
    int col0 = blockIdx.x * 128 + wc * 64;
    int l15 = lane & 15, q = lane >> 4;

    f32x4 acc[4][4] = {};
    const short* Abase = A + (size_t)(row0 + l15) * K + q * 8;
    const short* Bbase = B + (size_t)(col0 + l15) * K + q * 8;
    int nk = K >> 5;
    for (int ks = 0; ks < nk; ks++) {
        bf16x8 a[4], b[4];
#pragma unroll
        for (int t = 0; t < 4; t++) {
            a[t] = *(const bf16x8*)(Abase + (size_t)t * 16 * K + ks * 32);
            b[t] = *(const bf16x8*)(Bbase + (size_t)t * 16 * K + ks * 32);
        }
#pragma unroll
        for (int ti = 0; ti < 4; ti++)
#pragma unroll
            for (int tj = 0; tj < 4; tj++)
                acc[ti][tj] = __builtin_amdgcn_mfma_f32_16x16x32_bf16(a[ti], b[tj], acc[ti][tj], 0, 0, 0);
    }
#pragma unroll
    for (int ti = 0; ti < 4; ti++) {
#pragma unroll
        for (int tj = 0; tj < 4; tj++) {
#pragma unroll
            for (int r = 0; r < 4; r++) {
                int row = row0 + ti * 16 + q * 4 + r;
                int col = col0 + tj * 16 + l15;
                float v = acc[ti][tj][r];
                if (EPI == 1) v = __builtin_amdgcn_rcpf(1.0f + __expf(-v));
                C[(size_t)row * N + col] = v;
            }
        }
    }
}

// ---------------- SpMM (gather by CSR) ----------------

// x1n[r][t] = bf16( relu( (sum_{s in N(r)} h1[s][t]) * norm_dst[r] + b1[t] ) * norm_src[r] )
__global__ void spmm1_kernel(const float* __restrict__ h1, const int* __restrict__ row_start,
                             const int* __restrict__ eidx, const float* __restrict__ norm_dst,
                             const float* __restrict__ norm_src, const float* __restrict__ b1,
                             unsigned short* __restrict__ x1n) {
    int r = blockIdx.x;
    int t = threadIdx.x;  // 256 threads
    int s = row_start[r], e = row_start[r + 1];
    float sum = 0.0f;
    int i = s;
    for (; i + 4 <= e; i += 4) {
        int n0 = eidx[i], n1 = eidx[i + 1], n2 = eidx[i + 2], n3 = eidx[i + 3];
        float v0 = h1[n0 * HD1 + t];
        float v1 = h1[n1 * HD1 + t];
        float v2 = h1[n2 * HD1 + t];
        float v3 = h1[n3 * HD1 + t];
        sum += v0 + v1 + v2 + v3;
    }
    for (; i < e; i++) sum += h1[eidx[i] * HD1 + t];
    float x = sum * norm_dst[r] + b1[t];
    x = fmaxf(x, 0.0f) * norm_src[r];
    x1n[r * HD1 + t] = f2bf(x);
}

// emb[r][t] = sum * norm_dst[r] + b2[t]; store fp32 to d_out and bf16 for decoder
__global__ void spmm2_kernel(const float* __restrict__ h2, const int* __restrict__ row_start,
                             const int* __restrict__ eidx, const float* __restrict__ norm_dst,
                             const float* __restrict__ b2, float* __restrict__ emb,
                             unsigned short* __restrict__ embb) {
    int r = blockIdx.x;
    int t = threadIdx.x;  // 128 threads
    int s = row_start[r], e = row_start[r + 1];
    float sum = 0.0f;
    int i = s;
    for (; i + 4 <= e; i += 4) {
        int n0 = eidx[i], n1 = eidx[i + 1], n2 = eidx[i + 2], n3 = eidx[i + 3];
        float v0 = h2[n0 * HD2 + t];
        float v1 = h2[n1 * HD2 + t];
        float v2 = h2[n2 * HD2 + t];
        float v3 = h2[n3 * HD2 + t];
        sum += v0 + v1 + v2 + v3;
    }
    for (; i < e; i++) sum += h2[eidx[i] * HD2 + t];
    float x = sum * norm_dst[r] + b2[t];
    emb[r * HD2 + t] = x;
    embb[r * HD2 + t] = f2bf(x);
}

// ---------------- launch ----------------

extern "C" void kernel_launch(void* const* d_in, const int* in_sizes, int n_in,
                              void* d_out, int out_size, void* d_ws, size_t ws_size,
                              hipStream_t stream) {
    const float* features = (const float*)d_in[0];
    const int* src = (const int*)d_in[1];
    const int* dst = (const int*)d_in[2];
    const float* W1 = (const float*)d_in[3];
    const float* b1 = (const float*)d_in[4];
    const float* W2 = (const float*)d_in[5];
    const float* b2 = (const float*)d_in[6];

    char* ws = (char*)d_ws;
    size_t o = 0;
    auto alloc = [&](size_t bytes) -> char* {
        char* p = ws + o;
        o = (o + bytes + 255) & ~(size_t)255;
        return p;
    };
    int* deg_out = (int*)alloc(NN * 4);
    int* deg_in  = (int*)alloc(NN * 4);
    int* cursor  = (int*)alloc(NN * 4);   // contiguous with deg_* (32768 % 256 == 0)
    float* norm_src = (float*)alloc(NN * 4);
    float* norm_dst = (float*)alloc(NN * 4);
    int* row_start  = (int*)alloc((NN + 1) * 4);
    int* eidx       = (int*)alloc(EE * 4);
    unsigned short* xn  = (unsigned short*)alloc((size_t)NN * IN_DIM * 2);
    unsigned short* w1t = (unsigned short*)alloc((size_t)HD1 * IN_DIM * 2);
    unsigned short* w2t = (unsigned short*)alloc((size_t)HD2 * HD1 * 2);
    float* h1 = (float*)alloc((size_t)NN * HD1 * 4);
    unsigned short* x1n = (unsigned short*)alloc((size_t)NN * HD1 * 2);
    float* h2 = (float*)alloc((size_t)NN * HD2 * 4);
    unsigned short* embb = (unsigned short*)alloc((size_t)NN * HD2 * 2);

    float* emb_out = (float*)d_out;
    float* logits_out = emb_out + (size_t)NN * HD2;

    // zero deg_out, deg_in, cursor in one shot (contiguous)
    hipMemsetAsync(deg_out, 0, (size_t)NN * 4 * 3, stream);

    deg_kernel<<<EE / 256, 256, 0, stream>>>(src, dst, deg_out, deg_in);
    norm_kernel<<<NN / 256, 256, 0, stream>>>(deg_out, deg_in, norm_src, norm_dst);
    scan_kernel<<<1, 256, 0, stream>>>(deg_in, row_start);
    fill_kernel<<<EE / 256, 256, 0, stream>>>(src, dst, row_start, cursor, eidx);

    scale_cast_kernel<<<(NN * IN_DIM / 4) / 256, 256, 0, stream>>>(
        (const float4*)features, norm_src, (ushort4*)xn);
    transpose_cast_kernel<<<(IN_DIM * HD1 + 255) / 256, 256, 0, stream>>>(W1, w1t, IN_DIM, HD1);
    transpose_cast_kernel<<<(HD1 * HD2 + 255) / 256, 256, 0, stream>>>(W2, w2t, HD1, HD2);

    // layer 1: h1 = xn @ W1
    gemm_tn<0><<<dim3(HD1 / 128, NN / 128), 256, 0, stream>>>(
        (const short*)xn, (const short*)w1t, h1, HD1, IN_DIM);
    spmm1_kernel<<<NN, HD1, 0, stream>>>(h1, row_start, eidx, norm_dst, norm_src, b1, x1n);

    // layer 2: h2 = x1n @ W2
    gemm_tn<0><<<dim3(HD2 / 128, NN / 128), 256, 0, stream>>>(
        (const short*)x1n, (const short*)w2t, h2, HD2, HD1);
    spmm2_kernel<<<NN, HD2, 0, stream>>>(h2, row_start, eidx, norm_dst, b2, emb_out, embb);

    // decoder: logits = sigmoid(emb @ emb^T)
    gemm_tn<1><<<dim3(NN / 128, NN / 128), 256, 0, stream>>>(
        (const short*)embb, (const short*)embb, logits_out, NN, HD2);
}